// Round 2
// baseline (215.837 us; speedup 1.0000x reference)
//
#include <hip/hip_runtime.h>
#include <math.h>

#define N_NODES 20000
#define N_PAD 20096            // N_NODES rounded up to 128 (GEMM M-tile)
#define N_EDGES 320000
#define IN_CH 512
#define HEADS 4
#define OUT_CH 128
#define HC 512                 // HEADS*OUT_CH
#define NEG_SLOPE 0.2f

// fused-kernel block partitions
#define CVX_BLOCKS 5024        // N_PAD*IN_CH/8/256
#define CVW_BLOCKS 64          // (IN_CH/64)*(HC/64)
#define CNT_BLOCKS 1250        // N_EDGES/256
#define ATT_BLOCKS 1250        // N_NODES/16 (wave per node, 16 waves/block)

typedef __attribute__((ext_vector_type(8))) short short8;
typedef __attribute__((ext_vector_type(4))) float float4v;

// ---------------- edge-index dtype detection (inline, deterministic) ----------------
__device__ __forceinline__ int detect_is64(const int* __restrict__ ei32) {
    int is64 = 1;
    #pragma unroll
    for (int i = 0; i < 32; i++) is64 &= (ei32[2 * i + 1] == 0);
    return is64;
}

__device__ __forceinline__ int edge_at(const void* ei, int is64, long long idx) {
    return is64 ? (int)((const long long*)ei)[idx] : ((const int*)ei)[idx];
}

__device__ __forceinline__ unsigned short f2bf(float f) {
    union { float f; unsigned u; } v; v.f = f;
    unsigned r = v.u + 0x7fffu + ((v.u >> 16) & 1u);   // RNE
    return (unsigned short)(r >> 16);
}

// decode 8 packed bf16 (uint4) -> 8 floats
__device__ __forceinline__ void bf8_decode(uint4 r, float* f) {
    f[0] = __uint_as_float(r.x << 16); f[1] = __uint_as_float(r.x & 0xffff0000u);
    f[2] = __uint_as_float(r.y << 16); f[3] = __uint_as_float(r.y & 0xffff0000u);
    f[4] = __uint_as_float(r.z << 16); f[5] = __uint_as_float(r.z & 0xffff0000u);
    f[6] = __uint_as_float(r.w << 16); f[7] = __uint_as_float(r.w & 0xffff0000u);
}

__device__ __forceinline__ float leaky(float t) { return t > 0.f ? t : NEG_SLOPE * t; }

// pick w[hd] from a float4 of per-head weights (hd in 0..3) without scratch
__device__ __forceinline__ float sel_head(float4 w, int hd) {
    float lo = (hd & 1) ? w.y : w.x;
    float hi = (hd & 1) ? w.w : w.z;
    return (hd & 2) ? hi : lo;
}

// ---------------- K1: fused convert_x + convert_w(transpose) + count ----------------
__global__ __launch_bounds__(256) void fusedA_kernel(const float* __restrict__ x,
                                                     const float* __restrict__ W,
                                                     unsigned short* __restrict__ xb,
                                                     unsigned short* __restrict__ Wt,
                                                     const void* __restrict__ ei,
                                                     int* __restrict__ counts) {
    __shared__ float tile[64][65];
    int b = blockIdx.x;
    if (b < CVX_BLOCKS) {
        size_t i = ((size_t)b * 256 + threadIdx.x) * 8;
        unsigned short o[8];
        if (i < (size_t)N_NODES * IN_CH) {
            float4 f0 = *(const float4*)&x[i];
            float4 f1 = *(const float4*)&x[i + 4];
            o[0] = f2bf(f0.x); o[1] = f2bf(f0.y); o[2] = f2bf(f0.z); o[3] = f2bf(f0.w);
            o[4] = f2bf(f1.x); o[5] = f2bf(f1.y); o[6] = f2bf(f1.z); o[7] = f2bf(f1.w);
        } else {
            for (int k = 0; k < 8; k++) o[k] = 0;
        }
        *(short8*)&xb[i] = *(short8*)o;
    } else if (b < CVX_BLOCKS + CVW_BLOCKS) {
        int idx = b - CVX_BLOCKS;
        int k0 = (idx & 7) * 64, n0 = (idx >> 3) * 64;
        int t = threadIdx.x, r = t >> 6, c = t & 63;
        for (int rr = r; rr < 64; rr += 4)
            tile[rr][c] = W[(size_t)(k0 + rr) * HC + n0 + c];
        __syncthreads();
        for (int rr = r; rr < 64; rr += 4)
            Wt[(size_t)(n0 + rr) * IN_CH + k0 + c] = f2bf(tile[c][rr]);
    } else {
        int is64 = detect_is64((const int*)ei);
        int e = (b - CVX_BLOCKS - CVW_BLOCKS) * 256 + threadIdx.x;
        if (e < N_EDGES) {
            int dst = edge_at(ei, is64, (long long)N_EDGES + e);
            atomicAdd(&counts[dst], 1);
        }
    }
}

// ---------------- bf16 MFMA GEMM: xlb[M,N](bf16) = A[M,K] @ Wt[N,K]^T ----------------
__global__ __launch_bounds__(256) void gemm_kernel(const unsigned short* __restrict__ A,
                                                   const unsigned short* __restrict__ Bt,
                                                   unsigned short* __restrict__ Cb) {
    __shared__ __align__(16) unsigned short As[128 * 32];
    __shared__ __align__(16) unsigned short Bs[128 * 32];
    const int bm = blockIdx.y * 128;
    const int bn = blockIdx.x * 128;
    const int t = threadIdx.x;
    const int wv = t >> 6, lane = t & 63;
    const int wm = wv & 1, wn = wv >> 1;
    const int lm = lane & 15, lk = lane >> 4;

    float4v acc[4][4];
    #pragma unroll
    for (int i = 0; i < 4; i++)
        #pragma unroll
        for (int j = 0; j < 4; j++) acc[i][j] = (float4v){0.f, 0.f, 0.f, 0.f};

    const int srow = t >> 2;
    const int skof = (t & 3) * 8;

    for (int k0 = 0; k0 < IN_CH; k0 += 32) {
        __syncthreads();
        #pragma unroll
        for (int q = 0; q < 2; q++) {
            const unsigned short* gA = A + (size_t)(bm + q * 64 + srow) * IN_CH + k0 + skof;
            const unsigned short* gB = Bt + (size_t)(bn + q * 64 + srow) * IN_CH + k0 + skof;
            __builtin_amdgcn_global_load_lds((const __attribute__((address_space(1))) void*)gA,
                                             (__attribute__((address_space(3))) void*)&As[q * 2048 + t * 8], 16, 0, 0);
            __builtin_amdgcn_global_load_lds((const __attribute__((address_space(1))) void*)gB,
                                             (__attribute__((address_space(3))) void*)&Bs[q * 2048 + t * 8], 16, 0, 0);
        }
        __syncthreads();

        short8 af[4], bf[4];
        #pragma unroll
        for (int i = 0; i < 4; i++)
            af[i] = *(const short8*)&As[(wm * 64 + i * 16 + lm) * 32 + lk * 8];
        #pragma unroll
        for (int j = 0; j < 4; j++)
            bf[j] = *(const short8*)&Bs[(wn * 64 + j * 16 + lm) * 32 + lk * 8];
        #pragma unroll
        for (int i = 0; i < 4; i++)
            #pragma unroll
            for (int j = 0; j < 4; j++)
                acc[i][j] = __builtin_amdgcn_mfma_f32_16x16x32_bf16(af[i], bf[j], acc[i][j], 0, 0, 0);
    }

    #pragma unroll
    for (int i = 0; i < 4; i++) {
        #pragma unroll
        for (int r = 0; r < 4; r++) {
            int row = bm + wm * 64 + i * 16 + lk * 4 + r;
            if (row < N_NODES) {
                #pragma unroll
                for (int j = 0; j < 4; j++) {
                    int col = bn + wn * 64 + j * 16 + lm;
                    Cb[(size_t)row * HC + col] = f2bf(acc[i][j][r]);
                }
            }
        }
    }
}

// ---------------- K3: fused scan (block 0) + attention halves (blocks 1..) ----------------
__global__ __launch_bounds__(1024) void scanattn_kernel(const int* __restrict__ counts,
                                                        int* __restrict__ offsets,
                                                        const unsigned short* __restrict__ xlb,
                                                        const float* __restrict__ att_s,
                                                        const float* __restrict__ att_d,
                                                        float* __restrict__ a_s,
                                                        float* __restrict__ a_d) {
    int b = blockIdx.x;
    if (b == 0) {
        // chunked exclusive scan: counts -> offsets
        const int CHUNK = 20;                 // 1024*20 = 20480 >= N_NODES
        int tid = threadIdx.x;
        int base = tid * CHUNK;
        int c[CHUNK];
        #pragma unroll
        for (int k = 0; k < CHUNK; k++) {
            int i = base + k;
            c[k] = (i < N_NODES) ? counts[i] : 0;
        }
        int pre[CHUNK];
        int sum = 0;
        #pragma unroll
        for (int k = 0; k < CHUNK; k++) { pre[k] = sum; sum += c[k]; }

        int lane = tid & 63, wvv = tid >> 6;
        int s = sum;
        #pragma unroll
        for (int off = 1; off < 64; off <<= 1) {
            int u = __shfl_up(s, off, 64);
            if (lane >= off) s += u;
        }
        __shared__ int wsum[16];
        if (lane == 63) wsum[wvv] = s;
        __syncthreads();
        if (tid < 16) {
            int u = wsum[tid];
            #pragma unroll
            for (int off = 1; off < 16; off <<= 1) {
                int w = __shfl_up(u, off, 64);
                if (tid >= off) u += w;
            }
            wsum[tid] = u;
        }
        __syncthreads();
        int wbase = (wvv == 0) ? 0 : wsum[wvv - 1];
        int excl = wbase + s - sum;
        #pragma unroll
        for (int k = 0; k < CHUNK; k++) {
            int i = base + k;
            if (i < N_NODES) offsets[i] = excl + pre[k];
        }
        if (tid == 1023) offsets[N_NODES] = wbase + s;
    } else {
        // a_s[n,h], a_d[n,h] — wave per node, 16 nodes per 1024-thread block
        int node = (b - 1) * 16 + (threadIdx.x >> 6);
        if (node >= N_NODES) return;
        int lane = threadIdx.x & 63;
        int hd = lane >> 4;
        uint4 r = *(const uint4*)&xlb[(size_t)node * HC + lane * 8];
        float f[8];
        bf8_decode(r, f);
        float4 s0 = *(const float4*)&att_s[lane * 8];
        float4 s1 = *(const float4*)&att_s[lane * 8 + 4];
        float4 d0 = *(const float4*)&att_d[lane * 8];
        float4 d1 = *(const float4*)&att_d[lane * 8 + 4];
        float s = f[0]*s0.x + f[1]*s0.y + f[2]*s0.z + f[3]*s0.w
                + f[4]*s1.x + f[5]*s1.y + f[6]*s1.z + f[7]*s1.w;
        float d = f[0]*d0.x + f[1]*d0.y + f[2]*d0.z + f[3]*d0.w
                + f[4]*d1.x + f[5]*d1.y + f[6]*d1.z + f[7]*d1.w;
        #pragma unroll
        for (int off = 1; off < 16; off <<= 1) {
            s += __shfl_xor(s, off, 64);
            d += __shfl_xor(d, off, 64);
        }
        if ((lane & 15) == 0) {
            a_s[node * 4 + hd] = s;
            a_d[node * 4 + hd] = d;
        }
    }
}

// ---------------- K4: scatter + per-edge weights ----------------
// Computes w[e,h] = exp(leaky(a_s[src,h]+a_d[dst,h])) here so gather's per-edge
// critical path is just row-load -> fma (weights become uniform s_loads there).
__global__ __launch_bounds__(256) void scatterw_kernel(const void* __restrict__ ei,
                                                       const int* __restrict__ offsets,
                                                       int* __restrict__ cursor,
                                                       int* __restrict__ sorted_src,
                                                       const float* __restrict__ a_s,
                                                       const float* __restrict__ a_d,
                                                       float* __restrict__ edge_w) {
    int is64 = detect_is64((const int*)ei);
    int e = blockIdx.x * 256 + threadIdx.x;
    if (e < N_EDGES) {
        int dst = edge_at(ei, is64, (long long)N_EDGES + e);
        int src = edge_at(ei, is64, e);
        int pos = offsets[dst] + atomicAdd(&cursor[dst], 1);
        sorted_src[pos] = src;
        float4 as4 = *(const float4*)&a_s[src * 4];
        float4 ad4 = *(const float4*)&a_d[dst * 4];
        float4 w;
        w.x = __expf(leaky(as4.x + ad4.x));
        w.y = __expf(leaky(as4.y + ad4.y));
        w.z = __expf(leaky(as4.z + ad4.z));
        w.w = __expf(leaky(as4.w + ad4.w));
        *(float4*)&edge_w[(size_t)pos * 4] = w;
    }
}

// ---------------- segment softmax + weighted gather ----------------
// 2 waves per node (alternating 4-edge chunks), partials combined via LDS.
// No max subtraction (logits bounded ~|8|; fp32 exp safe; algebraically identical).
// Lane owns channels lane*8..+7 => head = lane>>4. Weights/indices are
// wave-uniform (scalar loads); only row loads use the vector-memory pipe.
__global__ __launch_bounds__(256) void gather_kernel(const unsigned short* __restrict__ xlb,
                                                     const float* __restrict__ a_s,
                                                     const float* __restrict__ a_d,
                                                     const int* __restrict__ offsets,
                                                     const int* __restrict__ sorted_src,
                                                     const float* __restrict__ edge_w,
                                                     const float* __restrict__ bias,
                                                     float* __restrict__ out) {
    __shared__ float cl[2][64][9];
    int wv = threadIdx.x >> 6;
    int nib = wv >> 1;                  // node in block (0..1)
    int sub = wv & 1;                   // which half-wave of the node
    int node = blockIdx.x * 2 + nib;    // grid = N_NODES/2, always < N_NODES
    int lane = threadIdx.x & 63;
    int hd = lane >> 4;
    int beg = offsets[node], end = offsets[node + 1];

    const unsigned short* xrow = xlb + lane * 8;
    float acc[8] = {0, 0, 0, 0, 0, 0, 0, 0};
    float denom = 0.f;

    if (sub == 0) {   // self-loop
        float4 as4 = *(const float4*)&a_s[node * 4];
        float4 ad4 = *(const float4*)&a_d[node * 4];
        float4 ws;
        ws.x = __expf(leaky(as4.x + ad4.x));
        ws.y = __expf(leaky(as4.y + ad4.y));
        ws.z = __expf(leaky(as4.z + ad4.z));
        ws.w = __expf(leaky(as4.w + ad4.w));
        float w = sel_head(ws, hd);
        denom = w;
        uint4 r = *(const uint4*)(xrow + (size_t)node * HC);
        float f[8];
        bf8_decode(r, f);
        #pragma unroll
        for (int k = 0; k < 8; k++) acc[k] = w * f[k];
    }

    for (int c0 = beg + sub * 4; c0 < end; c0 += 8) {
        int n = end - c0;
        if (n >= 4) {
            int s0 = sorted_src[c0];
            int s1 = sorted_src[c0 + 1];
            int s2 = sorted_src[c0 + 2];
            int s3 = sorted_src[c0 + 3];
            uint4 r0 = *(const uint4*)(xrow + (size_t)s0 * HC);
            uint4 r1 = *(const uint4*)(xrow + (size_t)s1 * HC);
            uint4 r2 = *(const uint4*)(xrow + (size_t)s2 * HC);
            uint4 r3 = *(const uint4*)(xrow + (size_t)s3 * HC);
            float4 wa = *(const float4*)&edge_w[(size_t)c0 * 4];
            float4 wb = *(const float4*)&edge_w[(size_t)(c0 + 1) * 4];
            float4 wc = *(const float4*)&edge_w[(size_t)(c0 + 2) * 4];
            float4 wd = *(const float4*)&edge_w[(size_t)(c0 + 3) * 4];
            float w0 = sel_head(wa, hd), w1 = sel_head(wb, hd);
            float w2 = sel_head(wc, hd), w3 = sel_head(wd, hd);
            denom += (w0 + w1) + (w2 + w3);
            float f0[8], f1[8], f2[8], f3[8];
            bf8_decode(r0, f0);
            bf8_decode(r1, f1);
            bf8_decode(r2, f2);
            bf8_decode(r3, f3);
            #pragma unroll
            for (int k = 0; k < 8; k++)
                acc[k] += (w0 * f0[k] + w1 * f1[k]) + (w2 * f2[k] + w3 * f3[k]);
        } else {
            for (int j = 0; j < n; j++) {
                int s0 = sorted_src[c0 + j];
                uint4 r0 = *(const uint4*)(xrow + (size_t)s0 * HC);
                float4 wa = *(const float4*)&edge_w[(size_t)(c0 + j) * 4];
                float w0 = sel_head(wa, hd);
                denom += w0;
                float f0[8];
                bf8_decode(r0, f0);
                #pragma unroll
                for (int k = 0; k < 8; k++) acc[k] += w0 * f0[k];
            }
        }
    }

    if (sub == 1) {
        #pragma unroll
        for (int k = 0; k < 8; k++) cl[nib][lane][k] = acc[k];
        cl[nib][lane][8] = denom;
    }
    __syncthreads();
    if (sub == 0) {
        #pragma unroll
        for (int k = 0; k < 8; k++) acc[k] += cl[nib][lane][k];
        denom += cl[nib][lane][8];

        float rd = 0.25f / (denom + 1e-16f);   // fold head-mean into normalize
        float v[8];
        #pragma unroll
        for (int k = 0; k < 8; k++) {
            float t = acc[k] * rd;
            t += __shfl_xor(t, 16, 64);
            t += __shfl_xor(t, 32, 64);
            v[k] = t;
        }
        if (hd == 0) {
            float4 b0 = *(const float4*)&bias[lane * 8];
            float4 b1 = *(const float4*)&bias[lane * 8 + 4];
            float o[8];
            o[0] = v[0] + b0.x; o[1] = v[1] + b0.y; o[2] = v[2] + b0.z; o[3] = v[3] + b0.w;
            o[4] = v[4] + b1.x; o[5] = v[5] + b1.y; o[6] = v[6] + b1.z; o[7] = v[7] + b1.w;
            #pragma unroll
            for (int k = 0; k < 8; k++) o[k] = o[k] > 0.f ? o[k] : expm1f(o[k]);
            *(float4*)&out[(size_t)node * OUT_CH + lane * 8]     = make_float4(o[0], o[1], o[2], o[3]);
            *(float4*)&out[(size_t)node * OUT_CH + lane * 8 + 4] = make_float4(o[4], o[5], o[6], o[7]);
        }
    }
}

// ---------------- launch ----------------
extern "C" void kernel_launch(void* const* d_in, const int* in_sizes, int n_in,
                              void* d_out, int out_size, void* d_ws, size_t ws_size,
                              hipStream_t stream) {
    const float* x       = (const float*)d_in[0];
    const float* W       = (const float*)d_in[1];
    const float* att_src = (const float*)d_in[2];
    const float* att_dst = (const float*)d_in[3];
    const float* bias    = (const float*)d_in[4];
    const void*  ei      = d_in[5];
    float* out = (float*)d_out;

    char* ws = (char*)d_ws;
    size_t off = 0;
    unsigned short* xlb = (unsigned short*)(ws + off); off += (size_t)N_PAD * HC * sizeof(unsigned short);
    float* a_s     = (float*)(ws + off); off += (size_t)N_NODES * HEADS * sizeof(float);
    float* a_d     = (float*)(ws + off); off += (size_t)N_NODES * HEADS * sizeof(float);
    int* counts    = (int*)(ws + off);   off += (size_t)N_NODES * sizeof(int);
    int* cursor    = (int*)(ws + off);   off += (size_t)N_NODES * sizeof(int);   // contiguous with counts
    int* offsets   = (int*)(ws + off);   off += (size_t)(N_NODES + 1) * sizeof(int);
    off = (off + 15) & ~(size_t)15;
    int* sorted_src = (int*)(ws + off);  off += (size_t)N_EDGES * sizeof(int);
    off = (off + 15) & ~(size_t)15;
    float* edge_w  = (float*)(ws + off); off += (size_t)N_EDGES * HEADS * sizeof(float);
    unsigned short* xb = (unsigned short*)(ws + off); off += (size_t)N_PAD * IN_CH * sizeof(unsigned short);
    unsigned short* Wt = (unsigned short*)(ws + off); off += (size_t)IN_CH * HC * sizeof(unsigned short);

    hipMemsetAsync(counts, 0, 2u * N_NODES * sizeof(int), stream);   // counts + cursor
    fusedA_kernel<<<CVX_BLOCKS + CVW_BLOCKS + CNT_BLOCKS, 256, 0, stream>>>(x, W, xb, Wt, ei, counts);
    gemm_kernel<<<dim3(HC / 128, N_PAD / 128), 256, 0, stream>>>(xb, Wt, xlb);
    scanattn_kernel<<<1 + ATT_BLOCKS, 1024, 0, stream>>>(counts, offsets, xlb, att_src, att_dst, a_s, a_d);
    scatterw_kernel<<<(N_EDGES + 255) / 256, 256, 0, stream>>>(ei, offsets, cursor, sorted_src, a_s, a_d, edge_w);
    gather_kernel<<<N_NODES / 2, 256, 0, stream>>>(xlb, a_s, a_d, offsets, sorted_src, edge_w, bias, out);
}